// Round 4
// baseline (90.184 us; speedup 1.0000x reference)
//
#include <hip/hip_runtime.h>

#define NROWS 1048576
#define NCLS 27
#define TROWS 64                    // rows per tile
#define TV4 (TROWS * NCLS / 4)      // 432 float4 per array per tile
#define NTILES (NROWS / TROWS)      // 16384
#define GRID 2048
#define TPB (NTILES / GRID)         // 8 tiles per block
#define SCALE 16777216.0            // 2^24 fixed-point for deterministic atomics

typedef __attribute__((address_space(3))) void       lds_vp;
typedef __attribute__((address_space(1))) const void glb_vp;

__device__ __forceinline__ void glds16(const float4* g, float4* l) {
  __builtin_amdgcn_global_load_lds((glb_vp*)g, (lds_vp*)l, 16, 0, 0);
}

__device__ __forceinline__ void stage_tile(
    const float* pred, const float* tgt, float4 (*sbuf4)[2][TV4],
    int b, int tile, int tid) {
  const float4* p4 = (const float4*)pred + (size_t)tile * TV4;
  const float4* t4 = (const float4*)tgt  + (size_t)tile * TV4;
  glds16(&p4[tid], &sbuf4[b][0][tid]);
  glds16(&t4[tid], &sbuf4[b][1][tid]);
  if (tid < TV4 - 256) {            // remainder: 176 vec4 per array
    glds16(&p4[256 + tid], &sbuf4[b][0][256 + tid]);
    glds16(&t4[256 + tid], &sbuf4[b][1][256 + tid]);
  }
}

__global__ __launch_bounds__(256) void l1pen_fused(
    const float* __restrict__ pred, const float* __restrict__ tgt,
    const float* __restrict__ pen,
    unsigned long long* __restrict__ wsum, unsigned int* __restrict__ wcnt,
    float* __restrict__ out) {
  __shared__ float4 sbuf4[2][2][TV4];      // 27648 B double-buffered tiles
  __shared__ float spen[NCLS * NCLS];      // 2916 B
  __shared__ float sred[4];
  const int tid = threadIdx.x;

  for (int i = tid; i < NCLS * NCLS; i += 256) spen[i] = pen[i];

  const int tile0 = blockIdx.x * TPB;
  stage_tile(pred, tgt, sbuf4, 0, tile0, tid);
  __syncthreads();

  // 4 threads per row: cols [0..6][7..13][14..20][21..26]
  const int q = tid & 3;
  const int r = tid >> 2;
  const int cbase = q * 7;
  float acc = 0.f;

  for (int t = 0; t < TPB; ++t) {
    const int cur = t & 1;
    if (t + 1 < TPB)
      stage_tile(pred, tgt, sbuf4, cur ^ 1, tile0 + t + 1, tid);

    const float* sp = (const float*)&sbuf4[cur][0][0];
    const float* st = (const float*)&sbuf4[cur][1][0];
    const float* rp = sp + r * NCLS + cbase;
    const float* rt = st + r * NCLS + cbase;

    float p0 = rp[0], t0 = rt[0];
    float l1 = fabsf(p0 - t0);
    float pb = p0, tb = t0;
    int pc = cbase, lc = cbase;
    #pragma unroll
    for (int j = 1; j < 7; ++j) {
      if (cbase + j < NCLS) {
        float p = rp[j], tt = rt[j];
        l1 += fabsf(p - tt);
        if (p > pb)  { pb = p;  pc = cbase + j; }
        if (tt > tb) { tb = tt; lc = cbase + j; }
      }
    }

    #pragma unroll
    for (int m = 1; m <= 2; m <<= 1) {
      float l1o = __shfl_xor(l1, m);
      float pbo = __shfl_xor(pb, m); int pco = __shfl_xor(pc, m);
      float tbo = __shfl_xor(tb, m); int lco = __shfl_xor(lc, m);
      l1 += l1o;
      if (pbo > pb || (pbo == pb && pco < pc)) { pb = pbo; pc = pco; }
      if (tbo > tb || (tbo == tb && lco < lc)) { tb = tbo; lc = lco; }
    }

    float pe = spen[pc * NCLS + lc];
    acc += (q == 0) ? l1 * pe : 0.f;

    __syncthreads();
  }

  // block reduce -> one fixed-point atomic per block (deterministic: i64 adds)
  #pragma unroll
  for (int off = 32; off; off >>= 1) acc += __shfl_down(acc, off);
  if ((tid & 63) == 0) sred[tid >> 6] = acc;
  __syncthreads();
  if (tid == 0) {
    float bp = (sred[0] + sred[1]) + (sred[2] + sred[3]);   // >= 0
    unsigned long long qv =
        (unsigned long long)(long long)llrint((double)bp * SCALE);
    atomicAdd(wsum, qv);
    __threadfence();
    unsigned int old = atomicAdd(wcnt, 1u);
    if (old == GRID - 1) {                 // last block finishes the mean
      __threadfence();
      unsigned long long s = atomicAdd(wsum, 0ull);   // coherent read
      out[0] = (float)(((double)(long long)s / SCALE) / (double)NROWS);
    }
  }
}

extern "C" void kernel_launch(void* const* d_in, const int* in_sizes, int n_in,
                              void* d_out, int out_size, void* d_ws, size_t ws_size,
                              hipStream_t stream) {
  const float* pred = (const float*)d_in[0];
  const float* tgt  = (const float*)d_in[1];
  const float* pen  = (const float*)d_in[2];
  float* out        = (float*)d_out;
  unsigned long long* wsum = (unsigned long long*)d_ws;
  unsigned int*       wcnt = (unsigned int*)((char*)d_ws + 8);

  hipMemsetAsync(d_ws, 0, 16, stream);     // re-zero accumulator + counter
  l1pen_fused<<<GRID, 256, 0, stream>>>(pred, tgt, pen, wsum, wcnt, out);
}

// Round 5
// 44.755 us; speedup vs baseline: 2.0150x; 2.0150x over previous
//
#include <hip/hip_runtime.h>

#define NROWS 1048576
#define NCLS 27
#define RPB 256                 // rows per block == threads per block
#define NBLK (NROWS / RPB)      // 4096

__global__ __launch_bounds__(256) void l1pen_partial(
    const float* __restrict__ pred, const float* __restrict__ tgt,
    const float* __restrict__ pen, float* __restrict__ partial) {
  __shared__ float sp[RPB * NCLS];          // 27648 B
  __shared__ float st[RPB * NCLS];          // 27648 B
  __shared__ float spen[NCLS * NCLS];       // 2916 B
  __shared__ float sred[4];
  const int tid = threadIdx.x;

  // penalty LUT -> LDS
  for (int i = tid; i < NCLS * NCLS; i += 256) spen[i] = pen[i];

  // coalesced float4 burst staging of 256 rows of pred/tgt
  const size_t base = (size_t)blockIdx.x * (RPB * NCLS);
  const float4* p4 = (const float4*)(pred + base);
  const float4* t4 = (const float4*)(tgt + base);
  float4* sp4 = (float4*)sp;
  float4* st4 = (float4*)st;
  constexpr int NV4 = RPB * NCLS / 4;       // 1728
  #pragma unroll
  for (int i = 0; i < NV4 / 256; ++i) {     // 6 full rounds
    sp4[tid + i * 256] = p4[tid + i * 256];
    st4[tid + i * 256] = t4[tid + i * 256];
  }
  {
    const int i = tid + (NV4 / 256) * 256;  // remainder: 192 vec4
    if (i < NV4) { sp4[i] = p4[i]; st4[i] = t4[i]; }
  }
  __syncthreads();

  // per-thread row: L1 sum + first-occurrence argmax of pred and tgt.
  // LDS lane stride 27 words -> gcd(27,32)=1 -> conflict-free.
  const float* rp = sp + tid * NCLS;
  const float* rt = st + tid * NCLS;
  float p0 = rp[0], t0 = rt[0];
  float l1 = fabsf(p0 - t0);
  float pbest = p0, tbest = t0;
  int pc = 0, lc = 0;
  #pragma unroll
  for (int c = 1; c < NCLS; ++c) {
    float p = rp[c], t = rt[c];
    l1 += fabsf(p - t);
    if (p > pbest) { pbest = p; pc = c; }
    if (t > tbest) { tbest = t; lc = c; }
  }
  float val = l1 * spen[pc * NCLS + lc];

  // wave64 tree reduce, then cross-wave via LDS
  #pragma unroll
  for (int off = 32; off; off >>= 1) val += __shfl_down(val, off);
  if ((tid & 63) == 0) sred[tid >> 6] = val;
  __syncthreads();
  if (tid == 0)
    partial[blockIdx.x] = (sred[0] + sred[1]) + (sred[2] + sred[3]);
}

__global__ __launch_bounds__(256) void l1pen_final(
    const float* __restrict__ partial, float* __restrict__ out) {
  __shared__ double sred[4];
  double s = 0.0;
  for (int i = threadIdx.x; i < NBLK; i += 256) s += (double)partial[i];
  #pragma unroll
  for (int off = 32; off; off >>= 1) s += __shfl_down(s, off);
  if ((threadIdx.x & 63) == 0) sred[threadIdx.x >> 6] = s;
  __syncthreads();
  if (threadIdx.x == 0)
    out[0] = (float)(((sred[0] + sred[1]) + (sred[2] + sred[3])) / (double)NROWS);
}

extern "C" void kernel_launch(void* const* d_in, const int* in_sizes, int n_in,
                              void* d_out, int out_size, void* d_ws, size_t ws_size,
                              hipStream_t stream) {
  const float* pred = (const float*)d_in[0];
  const float* tgt  = (const float*)d_in[1];
  const float* pen  = (const float*)d_in[2];
  float* out        = (float*)d_out;
  float* partial    = (float*)d_ws;   // 4096 floats = 16 KB scratch

  l1pen_partial<<<NBLK, 256, 0, stream>>>(pred, tgt, pen, partial);
  l1pen_final<<<1, 256, 0, stream>>>(partial, out);
}